// Round 1
// baseline (107.381 us; speedup 1.0000x reference)
//
#include <hip/hip_runtime.h>

// BEVPoolV2: out[v][c] = sum_{j=0..39} depth_2d[ranks_depth[v*40+j]] * feat_2d[ranks_feat[v*40+j]][c]
// Shapes (fixed by the reference):
//   depth: (1,6,118,16,44) fp32  -> 498432 scalars (+1 virtual zero row)
//   feat : (1,6,16,44,64)  fp32  -> 4224 rows of C=64 (+1 virtual zero row)
//   ranks_depth/ranks_feat: 1,600,000 int32 (values may equal the row count -> zero row)
//   out  : (1,1,200,200,64) fp32 -> 40000 voxels x 64 channels

#define ND_ROWS (1 * 6 * 118 * 16 * 44) // 498432
#define NF_ROWS (1 * 6 * 16 * 44)       // 4224
#define C_CH 64
#define MAXN_PTS 40
#define NVOX (200 * 200) // 40000
#define WAVES_PER_BLOCK 4

__global__ __launch_bounds__(256) void BEVPoolV2_79783312491037_kernel(
    const float* __restrict__ depth,
    const float* __restrict__ feat,
    const int* __restrict__ ranks_depth,
    const int* __restrict__ ranks_feat,
    float* __restrict__ out)
{
    const int lane = threadIdx.x & 63;
    const int wave = threadIdx.x >> 6;
    const int v = blockIdx.x * WAVES_PER_BLOCK + wave;
    if (v >= NVOX) return;

    const int pbase = v * MAXN_PTS;

    // Lanes 0..39 preload this voxel's 40 index pairs + depth scalars in parallel.
    int rd = ND_ROWS;
    int rf = NF_ROWS;
    if (lane < MAXN_PTS) {
        rd = ranks_depth[pbase + lane];
        rf = ranks_feat[pbase + lane];
    }
    // Fold zero-pad-row semantics into the depth scalar: if either index hits the
    // appended zero row, the point contributes 0.
    float dval = 0.0f;
    if (rd < ND_ROWS && rf < NF_ROWS) dval = depth[rd];
    const int rfc = (rf < NF_ROWS) ? rf : 0; // clamped for a safe (ignored) gather

    float acc = 0.0f;
#pragma unroll
    for (int j = 0; j < MAXN_PTS; ++j) {
        // j is a literal after unrolling -> v_readlane (scalar broadcast), no LDS.
        const float dj = __shfl(dval, j, 64);
        const int rfj = __shfl(rfc, j, 64);
        // Coalesced 256 B/wave gather of one feat row (L2-resident).
        const float f = feat[rfj * C_CH + lane];
        acc = fmaf(dj, f, acc);
    }

    out[v * C_CH + lane] = acc;
}

extern "C" void kernel_launch(void* const* d_in, const int* in_sizes, int n_in,
                              void* d_out, int out_size, void* d_ws, size_t ws_size,
                              hipStream_t stream)
{
    const float* depth       = (const float*)d_in[0];
    const float* feat        = (const float*)d_in[1];
    const int*   ranks_depth = (const int*)d_in[2];
    const int*   ranks_feat  = (const int*)d_in[3];
    // d_in[4] is maxn (=40), hardcoded as MAXN_PTS.
    float* out = (float*)d_out;

    const int blocks = NVOX / WAVES_PER_BLOCK; // 10000
    BEVPoolV2_79783312491037_kernel<<<blocks, 256, 0, stream>>>(
        depth, feat, ranks_depth, ranks_feat, out);
}